// Round 8
// baseline (866.597 us; speedup 1.0000x reference)
//
#include <hip/hip_runtime.h>
#include <stdint.h>

#define Bn 2048
#define Tn 512
#define An 32
#define Hn 16

#define SEG_CAP 131072
#define WS_HIST 8        // hist[len] at ws[WS_HIST+len], len in 1..512
#define WS_CURS 1024     // descending-order bucket cursors
#define WS_SSEG 4096     // sorted segment list (u32 packed: row<<19 | t0<<10 | len)

typedef __attribute__((ext_vector_type(8))) short bf16x8;
typedef __attribute__((ext_vector_type(4))) float f32x4;

union FragU { bf16x8 v; uint32_t u[4]; };

static __device__ __forceinline__ uint32_t pack_hi16(float a, float b){
  return (__float_as_uint(b) & 0xFFFF0000u) | (__float_as_uint(a) >> 16);
}
static __device__ __forceinline__ void split8(const float* s, FragU& hi, FragU& lo){
#pragma unroll
  for (int d = 0; d < 4; ++d){
    float a = s[2*d], b = s[2*d+1];
    float ah = __uint_as_float(__float_as_uint(a) & 0xFFFF0000u);
    float bh = __uint_as_float(__float_as_uint(b) & 0xFFFF0000u);
    hi.u[d] = pack_hi16(a, b);
    lo.u[d] = pack_hi16(a - ah, b - bh);
  }
}
static __device__ __forceinline__ uint32_t plo(uint32_t e, uint32_t o){
  return __builtin_amdgcn_perm(o, e, 0x05040100u);
}
static __device__ __forceinline__ f32x4 MF(const FragU& a, const FragU& b, f32x4 c){
  return __builtin_amdgcn_mfma_f32_16x16x32_bf16(a.v, b.v, c, 0, 0, 0);
}
// BHh = [bf16(h) | bf16(h)] duplicated halves via wave bpermute
static __device__ __forceinline__ void buildBHh(const uint32_t* pk, int srcA, int srcB,
                                                FragU& BHh){
  uint32_t d0 = (uint32_t)__builtin_amdgcn_ds_bpermute(srcA, (int)pk[0]);
  uint32_t d1 = (uint32_t)__builtin_amdgcn_ds_bpermute(srcA, (int)pk[1]);
  uint32_t d2 = (uint32_t)__builtin_amdgcn_ds_bpermute(srcA, (int)pk[2]);
  uint32_t d3 = (uint32_t)__builtin_amdgcn_ds_bpermute(srcA, (int)pk[3]);
  uint32_t d4 = (uint32_t)__builtin_amdgcn_ds_bpermute(srcB, (int)pk[0]);
  uint32_t d5 = (uint32_t)__builtin_amdgcn_ds_bpermute(srcB, (int)pk[1]);
  uint32_t d6 = (uint32_t)__builtin_amdgcn_ds_bpermute(srcB, (int)pk[2]);
  uint32_t d7 = (uint32_t)__builtin_amdgcn_ds_bpermute(srcB, (int)pk[3]);
  BHh.u[0] = plo(d0, d1); BHh.u[1] = plo(d2, d3);
  BHh.u[2] = plo(d4, d5); BHh.u[3] = plo(d6, d7);
}

// ================== segmentation prep kernels ==================
// Segments: boundaries at every t>0 with mask==0 (state reset) plus t=0.
// All segments start from zero state except t0==0 (uses h0*m0).

__global__ void seg_count(const float* __restrict__ masks, uint32_t* __restrict__ ws){
  int row = blockIdx.x * 64 + threadIdx.x;
  if (row >= Bn) return;
  const float* mr = &masks[(size_t)row * Tn];
  int prev = 0;
  for (int t = 1; t < Tn; ++t){
    if (mr[t] == 0.0f){ atomicAdd(&ws[WS_HIST + (t - prev)], 1u); prev = t; }
  }
  atomicAdd(&ws[WS_HIST + (Tn - prev)], 1u);
}

// descending-length bucket offsets via 1-wave suffix scan; writes nseg (ws[2]) & nbundles (ws[1])
__global__ void seg_offsets(uint32_t* __restrict__ ws){
  const int l = threadIdx.x;          // lane l covers lens 512-8l .. 512-8l-7 (descending)
  uint32_t h[8]; uint32_t s = 0;
#pragma unroll
  for (int j = 0; j < 8; ++j){ int len = 512 - (l*8 + j); h[j] = ws[WS_HIST + len]; s += h[j]; }
  uint32_t v = s;
  for (int d = 1; d < 64; d <<= 1){ uint32_t t = __shfl_up(v, d); if (l >= d) v += t; }
  uint32_t run = v - s;               // exclusive prefix over descending blocks
#pragma unroll
  for (int j = 0; j < 8; ++j){ int len = 512 - (l*8 + j); ws[WS_CURS + len] = run; run += h[j]; }
  if (l == 63){ ws[2] = run; ws[1] = (run + 15u) >> 4; }
}

__global__ void seg_place(const float* __restrict__ masks, uint32_t* __restrict__ ws){
  int row = blockIdx.x * 64 + threadIdx.x;
  if (row >= Bn) return;
  const float* mr = &masks[(size_t)row * Tn];
  int prev = 0;
  for (int t = 1; t < Tn; ++t){
    if (mr[t] == 0.0f){
      int len = t - prev;
      uint32_t idx = atomicAdd(&ws[WS_CURS + len], 1u);
      if (idx < SEG_CAP)
        ws[WS_SSEG + idx] = ((uint32_t)row << 19) | ((uint32_t)prev << 10) | (uint32_t)len;
      prev = t;
    }
  }
  int len = Tn - prev;
  uint32_t idx = atomicAdd(&ws[WS_CURS + len], 1u);
  if (idx < SEG_CAP)
    ws[WS_SSEG + idx] = ((uint32_t)row << 19) | ((uint32_t)prev << 10) | (uint32_t)len;
}

// ================== segmented LSTM kernel ==================
// One wave per bundle of 16 segments (grid-stride). R7 step math; no masks in loop.
__global__ __launch_bounds__(64, 2)
void lstm_seg(const float* __restrict__ xin, const float* __restrict__ masks,
              const float* __restrict__ h0, const float* __restrict__ c0,
              const float* __restrict__ w_ih, const float* __restrict__ w_hh,
              const float* __restrict__ b_ih, const float* __restrict__ b_hh,
              const float* __restrict__ w_act, const float* __restrict__ b_act,
              const float* __restrict__ w_cr, const float* __restrict__ b_cr,
              float* __restrict__ actor, float* __restrict__ critic,
              float* __restrict__ hT, float* __restrict__ cT,
              const uint32_t* __restrict__ ws)
{
  const int l = threadIdx.x;
  const int q = l >> 4;
  const int n = l & 15;
  const int colbase = (q & 1) * 8;

  const float KS = -1.44269504088896f;
  const float KG =  2.88539008177793f;

  // ---- weights (R7 exact: x-part hi/lo split, h-part single [Whi|Wlo]) ----
  FragU wihH0, wihL0, whhA0; f32x4 bias0;
  FragU wihH1, wihL1, whhA1; f32x4 bias1;
  FragU wihH2, wihL2, whhA2; f32x4 bias2;
  FragU wihH3, wihL3, whhA3; f32x4 bias3;
  {
    auto loadGate = [&](int g, float sc, FragU& wh, FragU& wl, FragU& a1, f32x4& bg){
      float tmp[8];
#pragma unroll
      for (int j = 0; j < 8; ++j) tmp[j] = w_ih[(g*16 + n)*32 + q*8 + j] * sc;
      split8(tmp, wh, wl);
#pragma unroll
      for (int j = 0; j < 8; ++j) tmp[j] = w_hh[(g*16 + n)*16 + colbase + j] * sc;
      FragU hh, hl; split8(tmp, hh, hl);
#pragma unroll
      for (int d = 0; d < 4; ++d) a1.u[d] = (q < 2) ? hh.u[d] : hl.u[d];
#pragma unroll
      for (int r = 0; r < 4; ++r)
        bg[r] = (b_ih[g*16 + q*4 + r] + b_hh[g*16 + q*4 + r]) * sc;
    };
    loadGate(0, KS, wihH0, wihL0, whhA0, bias0);
    loadGate(1, KS, wihH1, wihL1, whhA1, bias1);
    loadGate(2, KG, wihH2, wihL2, whhA2, bias2);
    loadGate(3, KS, wihH3, wihL3, whhA3, bias3);
  }
  FragU whA0, whA1f, wcA;
  f32x4 biasA0, biasA1;
  const float bcr = b_cr[0];
  {
    float tmp[8];
#pragma unroll
    for (int j = 0; j < 8; ++j) tmp[j] = w_act[(0*16 + n)*16 + colbase + j];
    { FragU hh, hl; split8(tmp, hh, hl);
#pragma unroll
      for (int d = 0; d < 4; ++d) whA0.u[d] = (q < 2) ? hh.u[d] : hl.u[d]; }
#pragma unroll
    for (int r = 0; r < 4; ++r) biasA0[r] = b_act[0*16 + q*4 + r];
#pragma unroll
    for (int j = 0; j < 8; ++j) tmp[j] = w_act[(1*16 + n)*16 + colbase + j];
    { FragU hh, hl; split8(tmp, hh, hl);
#pragma unroll
      for (int d = 0; d < 4; ++d) whA1f.u[d] = (q < 2) ? hh.u[d] : hl.u[d]; }
#pragma unroll
    for (int r = 0; r < 4; ++r) biasA1[r] = b_act[1*16 + q*4 + r];
#pragma unroll
    for (int j = 0; j < 8; ++j) tmp[j] = (n == 0) ? w_cr[colbase + j] : 0.0f;
    { FragU hh, hl; split8(tmp, hh, hl);
#pragma unroll
      for (int d = 0; d < 4; ++d) wcA.u[d] = (q < 2) ? hh.u[d] : hl.u[d]; }
  }

  const int srcA = (((q & 1) * 2) * 16 + n) * 4;
  const int srcB = srcA + 64;
  const f32x4 zero4 = {0.f, 0.f, 0.f, 0.f};

  const uint32_t nseg = ws[2];
  const uint32_t nb   = ws[1];
  const uint32_t* sseg = &ws[WS_SSEG];

  for (uint32_t b = blockIdx.x; b < nb; b += gridDim.x){
    const uint32_t idx = b * 16u + (uint32_t)n;
    const uint32_t sv = (idx < nseg) ? sseg[idx] : 0u;
    const int srow = (int)(sv >> 19);
    const int st0  = (int)((sv >> 10) & 0x1FFu);
    const int slen = (int)(sv & 0x3FFu);
    int ml = slen;
    { int o;
      o = __shfl_xor(ml, 1); ml = ml > o ? ml : o;
      o = __shfl_xor(ml, 2); ml = ml > o ? ml : o;
      o = __shfl_xor(ml, 4); ml = ml > o ? ml : o;
      o = __shfl_xor(ml, 8); ml = ml > o ? ml : o; }
    if (ml == 0) continue;                        // wave-uniform
    const int lm1 = (slen > 0) ? (slen - 1) : 0;

    // state: zero, except t0==0 segments use h0*m0 (reference semantics)
    float cs[4], hs[4];
    {
      const float m0 = masks[(size_t)srow * Tn];
      const bool z = (st0 == 0);
#pragma unroll
      for (int r = 0; r < 4; ++r){
        float hv = h0[srow*16 + q*4 + r] * m0;
        float cv = c0[srow*16 + q*4 + r] * m0;
        hs[r] = z ? hv : 0.f;
        cs[r] = z ? cv : 0.f;
      }
    }
    uint32_t pk[4];
#pragma unroll
    for (int r = 0; r < 4; ++r) pk[r] = __float_as_uint(hs[r]) >> 16;
    FragU BHh;
    buildBHh(pk, srcA, srcB, BHh);

    const size_t xbase = ((size_t)srow * Tn + st0) * 32 + q * 8;
    const size_t obase = (size_t)srow * Tn + st0;

    float4 xA[4], xB[4];
#pragma unroll
    for (int u = 0; u < 4; ++u){
      int sc = u < lm1 ? u : lm1;
      const float* p = &xin[xbase + (size_t)sc * 32];
      xA[u] = *(const float4*)p;
      xB[u] = *(const float4*)(p + 4);
    }

    for (int s0 = 0; s0 < ml; s0 += 4){
#pragma unroll
      for (int u = 0; u < 4; ++u){
        const int s = s0 + u;

        FragU Xh, Xl;
        {
          float sarr[8] = {xA[u].x, xA[u].y, xA[u].z, xA[u].w,
                           xB[u].x, xB[u].y, xB[u].z, xB[u].w};
          split8(sarr, Xh, Xl);
        }
        {
          int sc = (s + 4) < lm1 ? (s + 4) : lm1;
          const float* p = &xin[xbase + (size_t)sc * 32];
          xA[u] = *(const float4*)p;
          xB[u] = *(const float4*)(p + 4);
        }

        // x-part MFMAs (R7 exact)
        f32x4 ax0 = MF(wihH0, Xh, bias0); ax0 = MF(wihH0, Xl, ax0); ax0 = MF(wihL0, Xh, ax0);
        f32x4 ax1 = MF(wihH1, Xh, bias1); ax1 = MF(wihH1, Xl, ax1); ax1 = MF(wihL1, Xh, ax1);
        f32x4 ax2 = MF(wihH2, Xh, bias2); ax2 = MF(wihH2, Xl, ax2); ax2 = MF(wihL2, Xh, ax2);
        f32x4 ax3 = MF(wihH3, Xh, bias3); ax3 = MF(wihH3, Xl, ax3);

        // h-part MFMAs
        f32x4 ah0 = MF(whhA0, BHh, zero4);
        f32x4 ah1 = MF(whhA1, BHh, zero4);
        f32x4 ah2 = MF(whhA2, BHh, zero4);
        f32x4 ah3 = MF(whhA3, BHh, zero4);

        // heads for s-1 (BHh = h_{s-1}); predicated per-lane
        if (s){
          f32x4 a0 = MF(whA0, BHh, biasA0);
          f32x4 a1 = MF(whA1f, BHh, biasA1);
          f32x4 cc = MF(wcA, BHh, zero4);
          if (s - 1 < slen){
            *(f32x4*)&actor[(obase + (s - 1)) * 32 + q*4]      = a0;
            *(f32x4*)&actor[(obase + (s - 1)) * 32 + 16 + q*4] = a1;
            if (q == 0) critic[obase + (s - 1)] = cc[0] + bcr;
          }
        }

        // activation + state update (m == 1 inside segments); freeze when done
        const bool act = (s < slen);
#pragma unroll
        for (int r = 0; r < 4; ++r){
          float gi = ax0[r] + ah0[r];
          float gf = ax1[r] + ah1[r];
          float gg = ax2[r] + ah2[r];
          float go = ax3[r] + ah3[r];
          float iv = __builtin_amdgcn_rcpf(1.0f + __builtin_amdgcn_exp2f(gi));
          float fv = __builtin_amdgcn_rcpf(1.0f + __builtin_amdgcn_exp2f(gf));
          float gr = __builtin_amdgcn_rcpf(1.0f + __builtin_amdgcn_exp2f(gg));
          float ov = __builtin_amdgcn_rcpf(1.0f + __builtin_amdgcn_exp2f(go));
          float gv = 1.0f - 2.0f * gr;
          float c2 = fv * cs[r] + iv * gv;
          float et = __builtin_amdgcn_rcpf(1.0f + __builtin_amdgcn_exp2f(c2 * KG));
          float h2 = ov - 2.0f * (ov * et);
          cs[r] = act ? c2 : cs[r];
          hs[r] = act ? h2 : hs[r];
          pk[r] = __float_as_uint(hs[r]) >> 16;
        }
        buildBHh(pk, srcA, srcB, BHh);
      }
    }

    // epilogue heads (only needed when ml is a multiple of 4: last head not yet stored)
    if ((ml & 3) == 0){
      f32x4 a0 = MF(whA0, BHh, biasA0);
      f32x4 a1 = MF(whA1f, BHh, biasA1);
      f32x4 cc = MF(wcA, BHh, zero4);
      if (slen == ml){
        *(f32x4*)&actor[(obase + (ml - 1)) * 32 + q*4]      = a0;
        *(f32x4*)&actor[(obase + (ml - 1)) * 32 + 16 + q*4] = a1;
        if (q == 0) critic[obase + (ml - 1)] = cc[0] + bcr;
      }
    }

    // final state for row-terminal segments
    if (slen > 0 && st0 + slen == Tn){
      *(float4*)&hT[srow*16 + q*4] = make_float4(hs[0], hs[1], hs[2], hs[3]);
      *(float4*)&cT[srow*16 + q*4] = make_float4(cs[0], cs[1], cs[2], cs[3]);
    }
  }
}

// ================== R7 fallback (proven 307 us) — used if ws too small ==================
__global__ __launch_bounds__(64, 1)
void lstm_fused(const float* __restrict__ xin, const float* __restrict__ masks,
                const float* __restrict__ h0, const float* __restrict__ c0,
                const float* __restrict__ w_ih, const float* __restrict__ w_hh,
                const float* __restrict__ b_ih, const float* __restrict__ b_hh,
                const float* __restrict__ w_act, const float* __restrict__ b_act,
                const float* __restrict__ w_cr, const float* __restrict__ b_cr,
                float* __restrict__ actor, float* __restrict__ critic,
                float* __restrict__ hT, float* __restrict__ cT)
{
  const int l = threadIdx.x;
  const int q = l >> 4;
  const int n = l & 15;
  const int b0 = blockIdx.x * 16;
  const int colbase = (q & 1) * 8;

  const float KS = -1.44269504088896f;
  const float KG =  2.88539008177793f;

  FragU wihH0, wihL0, whhA0; f32x4 bias0;
  FragU wihH1, wihL1, whhA1; f32x4 bias1;
  FragU wihH2, wihL2, whhA2; f32x4 bias2;
  FragU wihH3, wihL3, whhA3; f32x4 bias3;
  {
    auto loadGate = [&](int g, float sc, FragU& wh, FragU& wl, FragU& a1, f32x4& bg){
      float tmp[8];
#pragma unroll
      for (int j = 0; j < 8; ++j) tmp[j] = w_ih[(g*16 + n)*32 + q*8 + j] * sc;
      split8(tmp, wh, wl);
#pragma unroll
      for (int j = 0; j < 8; ++j) tmp[j] = w_hh[(g*16 + n)*16 + colbase + j] * sc;
      FragU hh, hl; split8(tmp, hh, hl);
#pragma unroll
      for (int d = 0; d < 4; ++d) a1.u[d] = (q < 2) ? hh.u[d] : hl.u[d];
#pragma unroll
      for (int r = 0; r < 4; ++r)
        bg[r] = (b_ih[g*16 + q*4 + r] + b_hh[g*16 + q*4 + r]) * sc;
    };
    loadGate(0, KS, wihH0, wihL0, whhA0, bias0);
    loadGate(1, KS, wihH1, wihL1, whhA1, bias1);
    loadGate(2, KG, wihH2, wihL2, whhA2, bias2);
    loadGate(3, KS, wihH3, wihL3, whhA3, bias3);
  }
  FragU whA0, whA1f, wcA;
  f32x4 biasA0, biasA1;
  const float bcr = b_cr[0];
  {
    float tmp[8];
#pragma unroll
    for (int j = 0; j < 8; ++j) tmp[j] = w_act[(0*16 + n)*16 + colbase + j];
    { FragU hh, hl; split8(tmp, hh, hl);
#pragma unroll
      for (int d = 0; d < 4; ++d) whA0.u[d] = (q < 2) ? hh.u[d] : hl.u[d]; }
#pragma unroll
    for (int r = 0; r < 4; ++r) biasA0[r] = b_act[0*16 + q*4 + r];
#pragma unroll
    for (int j = 0; j < 8; ++j) tmp[j] = w_act[(1*16 + n)*16 + colbase + j];
    { FragU hh, hl; split8(tmp, hh, hl);
#pragma unroll
      for (int d = 0; d < 4; ++d) whA1f.u[d] = (q < 2) ? hh.u[d] : hl.u[d]; }
#pragma unroll
    for (int r = 0; r < 4; ++r) biasA1[r] = b_act[1*16 + q*4 + r];
#pragma unroll
    for (int j = 0; j < 8; ++j) tmp[j] = (n == 0) ? w_cr[colbase + j] : 0.0f;
    { FragU hh, hl; split8(tmp, hh, hl);
#pragma unroll
      for (int d = 0; d < 4; ++d) wcA.u[d] = (q < 2) ? hh.u[d] : hl.u[d]; }
  }

  const int srcA = (((q & 1) * 2) * 16 + n) * 4;
  const int srcB = srcA + 64;

  float cs[4], hs[4];
#pragma unroll
  for (int r = 0; r < 4; ++r){
    hs[r] = h0[(b0 + n)*16 + q*4 + r];
    cs[r] = c0[(b0 + n)*16 + q*4 + r];
  }
  uint32_t pk[4];
#pragma unroll
  for (int r = 0; r < 4; ++r) pk[r] = __float_as_uint(hs[r]) >> 16;
  FragU BHh;
  buildBHh(pk, srcA, srcB, BHh);

  const f32x4 zero4 = {0.f, 0.f, 0.f, 0.f};
  const size_t xrow = (size_t)(b0 + n) * Tn * 32 + q * 8;
  float4 xA[4], xB[4];
#pragma unroll
  for (int u = 0; u < 4; ++u){
    xA[u] = *(const float4*)&xin[xrow + (size_t)u * 32];
    xB[u] = *(const float4*)&xin[xrow + (size_t)u * 32 + 4];
  }
  const size_t mrow = (size_t)(b0 + n) * Tn;
  float4 mQ = *(const float4*)&masks[mrow];

  for (int t0 = 0; t0 < Tn; t0 += 4){
    const int tb = (t0 + 4 < Tn) ? (t0 + 4) : 0;
    float4 mN = *(const float4*)&masks[mrow + tb];
#pragma unroll
    for (int u = 0; u < 4; ++u){
      const int t = t0 + u;
      const float m = (u == 0) ? mQ.x : (u == 1) ? mQ.y : (u == 2) ? mQ.z : mQ.w;
      FragU Xh, Xl;
      {
        float s[8] = {xA[u].x, xA[u].y, xA[u].z, xA[u].w,
                      xB[u].x, xB[u].y, xB[u].z, xB[u].w};
        split8(s, Xh, Xl);
      }
      {
        const int tn = (t + 4 < Tn) ? (t + 4) : t;
        xA[u] = *(const float4*)&xin[xrow + (size_t)tn * 32];
        xB[u] = *(const float4*)&xin[xrow + (size_t)tn * 32 + 4];
      }
      f32x4 ax0 = MF(wihH0, Xh, bias0); ax0 = MF(wihH0, Xl, ax0); ax0 = MF(wihL0, Xh, ax0);
      f32x4 ax1 = MF(wihH1, Xh, bias1); ax1 = MF(wihH1, Xl, ax1); ax1 = MF(wihL1, Xh, ax1);
      f32x4 ax2 = MF(wihH2, Xh, bias2); ax2 = MF(wihH2, Xl, ax2); ax2 = MF(wihL2, Xh, ax2);
      f32x4 ax3 = MF(wihH3, Xh, bias3); ax3 = MF(wihH3, Xl, ax3);
      f32x4 ah0 = MF(whhA0, BHh, zero4);
      f32x4 ah1 = MF(whhA1, BHh, zero4);
      f32x4 ah2 = MF(whhA2, BHh, zero4);
      f32x4 ah3 = MF(whhA3, BHh, zero4);
      if (t){
        const int th = t - 1;
        f32x4 a0 = MF(whA0, BHh, biasA0);
        *(f32x4*)&actor[((size_t)(b0 + n) * Tn + th) * 32 + q*4] = a0;
        f32x4 a1 = MF(whA1f, BHh, biasA1);
        *(f32x4*)&actor[((size_t)(b0 + n) * Tn + th) * 32 + 16 + q*4] = a1;
        f32x4 cc = MF(wcA, BHh, zero4);
        if (q == 0) critic[(size_t)(b0 + n) * Tn + th] = cc[0] + bcr;
      }
#pragma unroll
      for (int r = 0; r < 4; ++r){
        float gi = ax0[r] + m * ah0[r];
        float gf = ax1[r] + m * ah1[r];
        float gg = ax2[r] + m * ah2[r];
        float go = ax3[r] + m * ah3[r];
        float iv = __builtin_amdgcn_rcpf(1.0f + __builtin_amdgcn_exp2f(gi));
        float fv = __builtin_amdgcn_rcpf(1.0f + __builtin_amdgcn_exp2f(gf));
        float gr = __builtin_amdgcn_rcpf(1.0f + __builtin_amdgcn_exp2f(gg));
        float ov = __builtin_amdgcn_rcpf(1.0f + __builtin_amdgcn_exp2f(go));
        float gv = 1.0f - 2.0f * gr;
        float c2 = fv * (cs[r] * m) + iv * gv;
        float et = __builtin_amdgcn_rcpf(1.0f + __builtin_amdgcn_exp2f(c2 * KG));
        float h2 = ov - 2.0f * (ov * et);
        cs[r] = c2;
        hs[r] = h2;
        pk[r] = __float_as_uint(h2) >> 16;
      }
      buildBHh(pk, srcA, srcB, BHh);
    }
    mQ = mN;
  }
  {
    const int th = Tn - 1;
    f32x4 a0 = MF(whA0, BHh, biasA0);
    *(f32x4*)&actor[((size_t)(b0 + n) * Tn + th) * 32 + q*4] = a0;
    f32x4 a1 = MF(whA1f, BHh, biasA1);
    *(f32x4*)&actor[((size_t)(b0 + n) * Tn + th) * 32 + 16 + q*4] = a1;
    f32x4 cc = MF(wcA, BHh, zero4);
    if (q == 0) critic[(size_t)(b0 + n) * Tn + th] = cc[0] + bcr;
  }
  *(float4*)&hT[(b0 + n)*16 + q*4] = make_float4(hs[0], hs[1], hs[2], hs[3]);
  *(float4*)&cT[(b0 + n)*16 + q*4] = make_float4(cs[0], cs[1], cs[2], cs[3]);
}

extern "C" void kernel_launch(void* const* d_in, const int* in_sizes, int n_in,
                              void* d_out, int out_size, void* d_ws, size_t ws_size,
                              hipStream_t stream) {
  (void)in_sizes; (void)n_in; (void)out_size;
  const float* xin   = (const float*)d_in[0];
  const float* masks = (const float*)d_in[1];
  const float* h0    = (const float*)d_in[2];
  const float* c0    = (const float*)d_in[3];
  const float* w_ih  = (const float*)d_in[4];
  const float* w_hh  = (const float*)d_in[5];
  const float* b_ih  = (const float*)d_in[6];
  const float* b_hh  = (const float*)d_in[7];
  const float* w_act = (const float*)d_in[8];
  const float* b_act = (const float*)d_in[9];
  const float* w_cr  = (const float*)d_in[10];
  const float* b_cr  = (const float*)d_in[11];

  float* out    = (float*)d_out;
  float* actor  = out;
  float* critic = out + (size_t)Bn * Tn * An;
  float* hT     = critic + (size_t)Bn * Tn;
  float* cT     = hT + (size_t)Bn * Hn;

  const size_t WS_NEED = (size_t)(WS_SSEG + SEG_CAP) * sizeof(uint32_t);
  if (d_ws != nullptr && ws_size >= WS_NEED){
    uint32_t* wsu = (uint32_t*)d_ws;
    hipMemsetAsync(d_ws, 0, 8192, stream);
    seg_count  <<<Bn/64, 64, 0, stream>>>(masks, wsu);
    seg_offsets<<<1,     64, 0, stream>>>(wsu);
    seg_place  <<<Bn/64, 64, 0, stream>>>(masks, wsu);
    lstm_seg   <<<2048,  64, 0, stream>>>(xin, masks, h0, c0, w_ih, w_hh, b_ih, b_hh,
                                          w_act, b_act, w_cr, b_cr,
                                          actor, critic, hT, cT, wsu);
  } else {
    lstm_fused<<<Bn/16, 64, 0, stream>>>(xin, masks, h0, c0, w_ih, w_hh, b_ih, b_hh,
                                         w_act, b_act, w_cr, b_cr,
                                         actor, critic, hT, cT);
  }
}